// Round 1
// baseline (332.933 us; speedup 1.0000x reference)
//
#include <hip/hip_runtime.h>

#define BB 4
#define CC 17
#define NN 4096
#define KN 7
#define CP 20                    // padded feature count (80B rows, float4-aligned)
#define NPTS (BB*NN)             // 16384
#define PAIRS (NPTS*KN)          // 114688
#define TT (CC*CC)               // 289

// ---------------- Stage 1: transpose logits (B,C,N)->(B*N,CP) + row norms ----
__global__ __launch_bounds__(256) void prep_kernel(const float* __restrict__ logits,
                                                   float* __restrict__ xt,
                                                   float* __restrict__ sq) {
    int i = blockIdx.x * blockDim.x + threadIdx.x;
    if (i >= NPTS) return;
    int b = i >> 12;            // i / NN
    int n = i & (NN - 1);       // i % NN
    const float* base = logits + (size_t)b * CC * NN + n;
    float v[CP];
    float s = 0.f;
#pragma unroll
    for (int c = 0; c < CC; ++c) { v[c] = base[(size_t)c * NN]; s = fmaf(v[c], v[c], s); }
#pragma unroll
    for (int c = CC; c < CP; ++c) v[c] = 0.f;
    float4* dst = (float4*)(xt + (size_t)i * CP);
#pragma unroll
    for (int q = 0; q < CP / 4; ++q)
        dst[q] = make_float4(v[4*q], v[4*q+1], v[4*q+2], v[4*q+3]);
    sq[i] = s;
}

// ---------------- Stage 2: per-row exact top-8 (dist, idx) lexicographic -----
// One wave (64 lanes) per row. Per-lane sorted top-8 over its 64 candidates,
// then 8 rounds of wave-wide pop-min (shfl_xor butterfly, tie-break low index).
__global__ __launch_bounds__(64) void topk_kernel(const float* __restrict__ xt,
                                                  const float* __restrict__ sq,
                                                  int* __restrict__ nidx) {
    int row  = blockIdx.x;          // 0..NPTS-1
    int b    = row >> 12;
    int lane = threadIdx.x;

    const float* xrow = xt + (size_t)row * CP;
    float q[CP];
#pragma unroll
    for (int c = 0; c < CP; ++c) q[c] = xrow[c];
    float sqn = sq[row];

    const float* xb  = xt + (size_t)b * NN * CP;
    const float* sqb = sq + (size_t)b * NN;

    float bd[8]; int bi[8];
#pragma unroll
    for (int s = 0; s < 8; ++s) { bd[s] = 3.4e38f; bi[s] = 0x7fffffff; }

    for (int t = 0; t < NN / 64; ++t) {
        int m = t * 64 + lane;
        const float4* xm4 = (const float4*)(xb + (size_t)m * CP);
        float dot = 0.f;
#pragma unroll
        for (int qq = 0; qq < CP / 4; ++qq) {
            float4 xv = xm4[qq];
            dot = fmaf(q[4*qq+0], xv.x, dot);
            dot = fmaf(q[4*qq+1], xv.y, dot);
            dot = fmaf(q[4*qq+2], xv.z, dot);
            dot = fmaf(q[4*qq+3], xv.w, dot);
        }
        float d = sqn + sqb[m] - 2.f * dot;
        // insert if lexicographically smaller than current worst
        bool better = (d < bd[7]) || (d == bd[7] && m < bi[7]);
        if (better) {
            bd[7] = d; bi[7] = m;
#pragma unroll
            for (int s = 7; s >= 1; --s) {
                bool sw = (bd[s] < bd[s-1]) || (bd[s] == bd[s-1] && bi[s] < bi[s-1]);
                if (sw) {
                    float td = bd[s]; bd[s] = bd[s-1]; bd[s-1] = td;
                    int   ti = bi[s]; bi[s] = bi[s-1]; bi[s-1] = ti;
                }
            }
        }
    }

    // wave-wide merge: 8 rounds of pop-min over lane heads
    int out_idx[8];
#pragma unroll
    for (int r = 0; r < 8; ++r) {
        float d = bd[0]; int j = bi[0];
#pragma unroll
        for (int off = 32; off >= 1; off >>= 1) {
            float od = __shfl_xor(d, off);
            int   oj = __shfl_xor(j, off);
            if (od < d || (od == d && oj < j)) { d = od; j = oj; }
        }
        out_idx[r] = j;
        // owning lane pops its head (indices are unique across lanes)
        if (bd[0] == d && bi[0] == j) {
#pragma unroll
            for (int s = 0; s < 7; ++s) { bd[s] = bd[s+1]; bi[s] = bi[s+1]; }
            bd[7] = 3.4e38f; bi[7] = 0x7fffffff;
        }
    }

    if (lane == 0) {
#pragma unroll
        for (int r = 1; r < 8; ++r)
            nidx[(size_t)row * KN + (r - 1)] = b * NN + out_idx[r];
    }
}

// ---------------- Stage 3: per-pair term, deterministic block partials ------
__global__ __launch_bounds__(256) void pair_kernel(const float* __restrict__ xt,
                                                   const int* __restrict__ labels,
                                                   const float* __restrict__ insT,
                                                   const int* __restrict__ nidx,
                                                   double* __restrict__ partials) {
    int p = blockIdx.x * blockDim.x + threadIdx.x;
    double local = 0.0;
    if (p < PAIRS) {
        int i = p / KN;
        int j = nidx[p];
        const float* xi = xt + (size_t)i * CP;
        const float* xj = xt + (size_t)j * CP;
        float d2 = 0.f;
#pragma unroll
        for (int c = 0; c < CP; ++c) { float df = xi[c] - xj[c]; d2 = fmaf(df, df, d2); }
        float eij = expf(-0.5f * d2);
        float sgn = (labels[j] == labels[i]) ? eij : -eij;
        const float* Ti = insT + (size_t)i * TT;
        const float* Tj = insT + (size_t)j * TT;
        float td = 0.f;
#pragma unroll 17
        for (int e = 0; e < TT; ++e) { float df = Ti[e] - Tj[e]; td = fmaf(df, df, td); }
        local = (double)sgn * (double)td;
    }
    __shared__ double red[256];
    int t = threadIdx.x;
    red[t] = local;
    __syncthreads();
    for (int s = 128; s > 0; s >>= 1) {
        if (t < s) red[t] += red[t + s];
        __syncthreads();
    }
    if (t == 0) partials[blockIdx.x] = red[0];
}

// ---------------- Stage 4: deterministic final reduce + mean ----------------
__global__ __launch_bounds__(512) void finalize_kernel(const double* __restrict__ partials,
                                                       int nparts, float* __restrict__ out) {
    __shared__ double red[512];
    int t = threadIdx.x;
    red[t] = (t < nparts) ? partials[t] : 0.0;
    __syncthreads();
    for (int s = 256; s > 0; s >>= 1) {
        if (t < s) red[t] += red[t + s];
        __syncthreads();
    }
    if (t == 0) out[0] = (float)(red[0] / (double)PAIRS);
}

extern "C" void kernel_launch(void* const* d_in, const int* in_sizes, int n_in,
                              void* d_out, int out_size, void* d_ws, size_t ws_size,
                              hipStream_t stream) {
    const float* logits = (const float*)d_in[0];   // (B,C,N) fp32
    const int*   labels = (const int*)d_in[1];     // (B,N) int32
    const float* insT   = (const float*)d_in[2];   // (B*N, C, C) fp32
    float* out = (float*)d_out;

    // workspace layout
    char* ws = (char*)d_ws;
    double* partials = (double*)ws;                          // 512 doubles = 4096 B
    float*  sq       = (float*)(ws + 4096);                  // 16384 f32  = 65536 B
    int*    nidx     = (int*)  (ws + 4096 + 65536);          // 114688 i32 = 458752 B
    float*  xt       = (float*)(ws + 4096 + 65536 + 458752); // 16384*20 f32 = 1310720 B

    hipLaunchKernelGGL(prep_kernel, dim3((NPTS + 255) / 256), dim3(256), 0, stream,
                       logits, xt, sq);
    hipLaunchKernelGGL(topk_kernel, dim3(NPTS), dim3(64), 0, stream,
                       xt, sq, nidx);
    int grid = (PAIRS + 255) / 256;  // 448
    hipLaunchKernelGGL(pair_kernel, dim3(grid), dim3(256), 0, stream,
                       xt, labels, insT, nidx, partials);
    hipLaunchKernelGGL(finalize_kernel, dim3(1), dim3(512), 0, stream,
                       partials, grid, out);
}

// Round 2
// 217.356 us; speedup vs baseline: 1.5317x; 1.5317x over previous
//
#include <hip/hip_runtime.h>

#define BB 4
#define CC 17
#define NN 4096
#define KN 7
#define CPX 24                   // padded row: 20 features + sq + 3 pad (96 B)
#define NPTS (BB*NN)             // 16384
#define PAIRS (NPTS*KN)          // 114688
#define TT (CC*CC)               // 289
#define FINF 3.4e38f

// ---- Stage 1: transpose logits (B,C,N) -> xs[B*N][24] = {17 feat, 3 zero, sq, 3 zero}
__global__ __launch_bounds__(256) void prep_kernel(const float* __restrict__ logits,
                                                   float* __restrict__ xs) {
    int i = blockIdx.x * blockDim.x + threadIdx.x;
    if (i >= NPTS) return;
    int b = i >> 12;
    int n = i & (NN - 1);
    const float* base = logits + (size_t)b * CC * NN + n;
    float v[CPX];
    float s = 0.f;
#pragma unroll
    for (int c = 0; c < CC; ++c) { v[c] = base[(size_t)c * NN]; s = fmaf(v[c], v[c], s); }
#pragma unroll
    for (int c = CC; c < 20; ++c) v[c] = 0.f;
    v[20] = s; v[21] = 0.f; v[22] = 0.f; v[23] = 0.f;
    float4* dst = (float4*)(xs + (size_t)i * CPX);
#pragma unroll
    for (int q = 0; q < CPX / 4; ++q)
        dst[q] = make_float4(v[4*q], v[4*q+1], v[4*q+2], v[4*q+3]);
}

// ---- Stage 2: lane = row, wave-uniform candidate stream (scalar-broadcast loads).
// Each wave: 64 rows (one group), one candidate slice of CS=4096/S candidates.
// Per row keep 8 smallest rank values r = sqb - 2*dot (set semantics, order free).
__global__ __launch_bounds__(64) void topk_slice_kernel(const float* __restrict__ xs,
                                                        float* __restrict__ parts_d,
                                                        int* __restrict__ parts_i,
                                                        int S, int CS) {
    int g    = blockIdx.x;            // 0..255 row-group (64 rows, single batch)
    int s    = blockIdx.y;            // 0..S-1 candidate slice
    int lane = threadIdx.x;
    int row  = g * 64 + lane;
    int b    = g >> 6;                // 64 groups per batch
    int cb   = __builtin_amdgcn_readfirstlane(b * NN + s * CS);

    const float4* qr = (const float4*)(xs + (size_t)row * CPX);
    float q[20];
#pragma unroll
    for (int c = 0; c < 5; ++c) {
        float4 t = qr[c];
        q[4*c] = t.x; q[4*c+1] = t.y; q[4*c+2] = t.z; q[4*c+3] = t.w;
    }

    float bd[8]; int bi[8];
#pragma unroll
    for (int k = 0; k < 8; ++k) { bd[k] = FINF; bi[k] = -1; }

#pragma unroll 2
    for (int m = 0; m < CS; ++m) {
        const float* cp = xs + (size_t)(cb + m) * CPX;   // wave-uniform -> s_load
        float a0 = 0.f, a1 = 0.f, a2 = 0.f, a3 = 0.f;
#pragma unroll
        for (int c = 0; c < 5; ++c) {
            float4 cv = ((const float4*)cp)[c];
            a0 = fmaf(q[4*c+0], cv.x, a0);
            a1 = fmaf(q[4*c+1], cv.y, a1);
            a2 = fmaf(q[4*c+2], cv.z, a2);
            a3 = fmaf(q[4*c+3], cv.w, a3);
        }
        float sb = cp[20];
        float d  = fmaf(-2.f, (a0 + a1) + (a2 + a3), sb);
        if (d < bd[7]) {
            bd[7] = d; bi[7] = cb + m;
#pragma unroll
            for (int k = 7; k >= 1; --k) {
                if (bd[k] < bd[k-1]) {
                    float td = bd[k]; bd[k] = bd[k-1]; bd[k-1] = td;
                    int   ti = bi[k]; bi[k] = bi[k-1]; bi[k-1] = ti;
                }
            }
        }
    }

    size_t o = ((size_t)row * S + s) * 8;
#pragma unroll
    for (int k = 0; k < 8; ++k) { parts_d[o + k] = bd[k]; parts_i[o + k] = bi[k]; }
}

// ---- Stage 3: per-row merge of 8*S pairs -> top-8, drop min (self), emit 7 idx.
// One wave per row; lane holds up to 2 pairs; 8 rounds of lex pop-min butterfly.
__global__ __launch_bounds__(256) void merge_kernel(const float* __restrict__ parts_d,
                                                    const int* __restrict__ parts_i,
                                                    int* __restrict__ nidx, int S) {
    int wid  = threadIdx.x >> 6;
    int lane = threadIdx.x & 63;
    int row  = blockIdx.x * 4 + wid;
    int P    = 8 * S;
    const float* pd = parts_d + (size_t)row * P;
    const int*   pi = parts_i + (size_t)row * P;

    float dA = FINF, dB = FINF;
    int   iA = 0x40000000 + lane, iB = 0x50000000 + lane;  // unique sentinels
    if (lane < P)      { dA = pd[lane];      iA = pi[lane]; }
    if (lane + 64 < P) { dB = pd[lane + 64]; iB = pi[lane + 64]; }
    if (dB < dA || (dB == dA && iB < iA)) {
        float td = dA; dA = dB; dB = td;
        int   ti = iA; iA = iB; iB = ti;
    }

#pragma unroll
    for (int r = 0; r < 8; ++r) {
        float d = dA; int j = iA;
#pragma unroll
        for (int off = 32; off >= 1; off >>= 1) {
            float od = __shfl_xor(d, off);
            int   oj = __shfl_xor(j, off);
            if (od < d || (od == d && oj < j)) { d = od; j = oj; }
        }
        if (r >= 1 && lane == 0) nidx[(size_t)row * KN + (r - 1)] = j;
        if (dA == d && iA == j) {       // exactly one owner (indices unique)
            dA = dB; iA = iB;
            dB = FINF; iB = 0x60000000 + lane;
        }
    }
}

// ---- Stage 4: per-pair term, deterministic block partials ------------------
__global__ __launch_bounds__(256) void pair_kernel(const float* __restrict__ xs,
                                                   const int* __restrict__ labels,
                                                   const float* __restrict__ insT,
                                                   const int* __restrict__ nidx,
                                                   double* __restrict__ partials) {
    int p = blockIdx.x * blockDim.x + threadIdx.x;
    double local = 0.0;
    if (p < PAIRS) {
        int i = p / KN;
        int j = nidx[p];
        const float* xi = xs + (size_t)i * CPX;
        const float* xj = xs + (size_t)j * CPX;
        float d2 = 0.f;
#pragma unroll
        for (int c = 0; c < 20; ++c) { float df = xi[c] - xj[c]; d2 = fmaf(df, df, d2); }
        float eij = expf(-0.5f * d2);
        float sgn = (labels[j] == labels[i]) ? eij : -eij;
        const float* Ti = insT + (size_t)i * TT;
        const float* Tj = insT + (size_t)j * TT;
        float td = 0.f;
#pragma unroll 17
        for (int e = 0; e < TT; ++e) { float df = Ti[e] - Tj[e]; td = fmaf(df, df, td); }
        local = (double)sgn * (double)td;
    }
    __shared__ double red[256];
    int t = threadIdx.x;
    red[t] = local;
    __syncthreads();
    for (int sft = 128; sft > 0; sft >>= 1) {
        if (t < sft) red[t] += red[t + sft];
        __syncthreads();
    }
    if (t == 0) partials[blockIdx.x] = red[0];
}

// ---- Stage 5: deterministic final reduce + mean ----------------------------
__global__ __launch_bounds__(512) void finalize_kernel(const double* __restrict__ partials,
                                                       int nparts, float* __restrict__ out) {
    __shared__ double red[512];
    int t = threadIdx.x;
    red[t] = (t < nparts) ? partials[t] : 0.0;
    __syncthreads();
    for (int sft = 256; sft > 0; sft >>= 1) {
        if (t < sft) red[t] += red[t + sft];
        __syncthreads();
    }
    if (t == 0) out[0] = (float)(red[0] / (double)PAIRS);
}

extern "C" void kernel_launch(void* const* d_in, const int* in_sizes, int n_in,
                              void* d_out, int out_size, void* d_ws, size_t ws_size,
                              hipStream_t stream) {
    const float* logits = (const float*)d_in[0];
    const int*   labels = (const int*)d_in[1];
    const float* insT   = (const float*)d_in[2];
    float* out = (float*)d_out;

    // pick slice count by workspace budget
    int S = 16;
    size_t fixed = 4096 /*partials*/ + 458752 /*nidx*/ + (size_t)NPTS * CPX * 4 /*xs*/;
    while (S > 1 && fixed + 2 * (size_t)NPTS * 8 * S * 4 > ws_size) S >>= 1;
    int CS = NN / S;

    char* ws = (char*)d_ws;
    double* partials = (double*)ws;
    int*    nidx     = (int*)(ws + 4096);
    float*  xs       = (float*)(ws + 4096 + 458752);
    float*  parts_d  = (float*)(ws + fixed);
    int*    parts_i  = (int*)(ws + fixed + (size_t)NPTS * 8 * S * 4);

    hipLaunchKernelGGL(prep_kernel, dim3((NPTS + 255) / 256), dim3(256), 0, stream,
                       logits, xs);
    hipLaunchKernelGGL(topk_slice_kernel, dim3(256, S), dim3(64), 0, stream,
                       xs, parts_d, parts_i, S, CS);
    hipLaunchKernelGGL(merge_kernel, dim3(NPTS / 4), dim3(256), 0, stream,
                       parts_d, parts_i, nidx, S);
    int grid = (PAIRS + 255) / 256;  // 448
    hipLaunchKernelGGL(pair_kernel, dim3(grid), dim3(256), 0, stream,
                       xs, labels, insT, nidx, partials);
    hipLaunchKernelGGL(finalize_kernel, dim3(1), dim3(512), 0, stream,
                       partials, grid, out);
}

// Round 3
// 167.071 us; speedup vs baseline: 1.9928x; 1.3010x over previous
//
#include <hip/hip_runtime.h>

#define BB 4
#define CC 17
#define NN 4096
#define KN 7
#define NPTS (BB*NN)             // 16384
#define PAIRS (NPTS*KN)          // 114688
#define TT (CC*CC)               // 289
#define FINF 3.4e38f
#define SLC 4                    // candidate slices per batch
#define CSL (NN/SLC)             // 1024 candidates per slice
#define NTIL (CSL/16)            // 64 tiles per slice

typedef float f32x4 __attribute__((ext_vector_type(4)));
typedef short short8 __attribute__((ext_vector_type(8)));

// ---- Stage 1: transpose logits -> xs fp32[16384][24], xb bf16[16384][32], sq
__global__ __launch_bounds__(256) void prep_kernel(const float* __restrict__ logits,
                                                   float* __restrict__ xs,
                                                   unsigned short* __restrict__ xb,
                                                   float* __restrict__ sq) {
    int i = blockIdx.x * blockDim.x + threadIdx.x;
    if (i >= NPTS) return;
    int b = i >> 12;
    int n = i & (NN - 1);
    const float* base = logits + (size_t)b * CC * NN + n;
    float v[24];
    float s = 0.f;
#pragma unroll
    for (int c = 0; c < CC; ++c) { v[c] = base[(size_t)c * NN]; s = fmaf(v[c], v[c], s); }
#pragma unroll
    for (int c = CC; c < 24; ++c) v[c] = 0.f;
    float4* dst = (float4*)(xs + (size_t)i * 24);
#pragma unroll
    for (int q = 0; q < 6; ++q)
        dst[q] = make_float4(v[4*q], v[4*q+1], v[4*q+2], v[4*q+3]);
    sq[i] = s;
    // bf16 row (RNE), K padded to 32 with zeros
    unsigned int w[16];
#pragma unroll
    for (int t = 0; t < 16; ++t) {
        unsigned int u0 = 0, u1 = 0;
        if (2*t < CC)     { unsigned int ub = __float_as_uint(v[2*t]);   u0 = (ub + 0x7FFFu + ((ub>>16)&1u)) >> 16; }
        if (2*t+1 < CC)   { unsigned int ub = __float_as_uint(v[2*t+1]); u1 = (ub + 0x7FFFu + ((ub>>16)&1u)) >> 16; }
        w[t] = u0 | (u1 << 16);
    }
    uint4* xd = (uint4*)(xb + (size_t)i * 32);
#pragma unroll
    for (int q = 0; q < 4; ++q)
        xd[q] = make_uint4(w[4*q], w[4*q+1], w[4*q+2], w[4*q+3]);
}

// ---- Stage 2: MFMA rank computation + per-lane top-8 + in-wave merge -------
// Wave = (strip of 16 rows, slice of 1024 candidates). Block = 4 strips, same slice.
__global__ __launch_bounds__(256) void topk_mfma_kernel(const unsigned short* __restrict__ xb,
                                                        const float* __restrict__ sq,
                                                        float* __restrict__ parts_d,
                                                        int* __restrict__ parts_i) {
    int wid   = threadIdx.x >> 6;
    int lane  = threadIdx.x & 63;
    int strip = blockIdx.x * 4 + wid;      // 0..1023
    int s     = blockIdx.y;                // 0..SLC-1
    int b     = strip >> 8;
    int cb    = b * NN + s * CSL;          // global candidate base
    int col   = lane & 15;
    int grp   = lane >> 4;
    int k0    = grp * 8;                   // k-chunk for A/B fragments

    // A fragment: 16 query rows x K32
    int arow = strip * 16 + col;
    short8 A = *reinterpret_cast<const short8*>(xb + (size_t)arow * 32 + k0);

    const unsigned short* bp = xb + (size_t)(cb + col) * 32 + k0;
    const float* sp = sq + cb + col;

    float bd[4][8]; int bi[4][8];
#pragma unroll
    for (int j = 0; j < 4; ++j)
#pragma unroll
        for (int k = 0; k < 8; ++k) { bd[j][k] = FINF; bi[j][k] = 0x100000 + lane*8 + k; }

    f32x4 z = {0.f, 0.f, 0.f, 0.f};
#pragma unroll 2
    for (int t = 0; t < NTIL; ++t) {
        short8 Bf = *reinterpret_cast<const short8*>(bp + (size_t)t * 16 * 32);
        float sqv = sp[t * 16];
        f32x4 acc = __builtin_amdgcn_mfma_f32_16x16x32_bf16(A, Bf, z, 0, 0, 0);
        int iv = t * 16 + col;             // slice-local candidate index
#pragma unroll
        for (int j = 0; j < 4; ++j) {
            float r = fmaf(-2.f, acc[j], sqv);
            if (r < bd[j][7]) {
                bd[j][7] = r; bi[j][7] = iv;
#pragma unroll
                for (int k = 7; k >= 1; --k) {
                    if (bd[j][k] < bd[j][k-1]) {
                        float td = bd[j][k]; bd[j][k] = bd[j][k-1]; bd[j][k-1] = td;
                        int   ti = bi[j][k]; bi[j][k] = bi[j][k-1]; bi[j][k-1] = ti;
                    }
                }
            }
        }
    }

    // merge 16 lanes' top-8 per row (within each 16-lane group), emit top-8
#pragma unroll
    for (int j = 0; j < 4; ++j) {
        int row = strip * 16 + grp * 4 + j;
        size_t ob = ((size_t)row * SLC + s) * 8;
#pragma unroll
        for (int r = 0; r < 8; ++r) {
            float d = bd[j][0]; int ii = bi[j][0];
#pragma unroll
            for (int off = 8; off >= 1; off >>= 1) {
                float od = __shfl_xor(d, off);
                int   oi = __shfl_xor(ii, off);
                if (od < d || (od == d && oi < ii)) { d = od; ii = oi; }
            }
            if (col == r) { parts_d[ob + r] = d; parts_i[ob + r] = cb + ii; }
            if (bd[j][0] == d && bi[j][0] == ii) {
#pragma unroll
                for (int k = 0; k < 7; ++k) { bd[j][k] = bd[j][k+1]; bi[j][k] = bi[j][k+1]; }
                bd[j][7] = FINF; bi[j][7] = 0x7f00000 + lane;
            }
        }
    }
}

// ---- Stage 3: per-row merge of 8*SLC pairs -> drop self (min), emit 7 idx --
__global__ __launch_bounds__(256) void merge_kernel(const float* __restrict__ parts_d,
                                                    const int* __restrict__ parts_i,
                                                    int* __restrict__ nidx) {
    int wid  = threadIdx.x >> 6;
    int lane = threadIdx.x & 63;
    int row  = blockIdx.x * 4 + wid;
    const int P = 8 * SLC;                 // 32
    const float* pd = parts_d + (size_t)row * P;
    const int*   pi = parts_i + (size_t)row * P;

    float dA = FINF; int iA = 0x40000000 + lane;
    if (lane < P) { dA = pd[lane]; iA = pi[lane]; }

#pragma unroll
    for (int r = 0; r < 8; ++r) {
        float d = dA; int j = iA;
#pragma unroll
        for (int off = 32; off >= 1; off >>= 1) {
            float od = __shfl_xor(d, off);
            int   oj = __shfl_xor(j, off);
            if (od < d || (od == d && oj < j)) { d = od; j = oj; }
        }
        if (r >= 1 && lane == 0) nidx[(size_t)row * KN + (r - 1)] = j;
        if (dA == d && iA == j) { dA = FINF; iA = 0x60000000 + lane; }
    }
}

// ---- Stage 4: wave-per-pair, coalesced T-row scan, 8 pairs per wave --------
__global__ __launch_bounds__(256) void pair_kernel(const float* __restrict__ xs,
                                                   const int* __restrict__ labels,
                                                   const float* __restrict__ insT,
                                                   const int* __restrict__ nidx,
                                                   double* __restrict__ partials) {
    int wid  = threadIdx.x >> 6;
    int lane = threadIdx.x & 63;
    int wv   = blockIdx.x * 4 + wid;       // 0..14335
    double acc = 0.0;
#pragma unroll 1
    for (int pp = 0; pp < 8; ++pp) {
        int p = wv * 8 + pp;               // < PAIRS by construction
        int i = p / KN;
        int j = nidx[p];
        const float* Ti = insT + (size_t)i * TT;
        const float* Tj = insT + (size_t)j * TT;
        float td = 0.f;
#pragma unroll
        for (int q = 0; q < 4; ++q) {
            int e = lane + 64 * q;
            float df = Ti[e] - Tj[e];
            td = fmaf(df, df, td);
        }
        if (lane < TT - 256) {             // 33 tail elements
            float df = Ti[lane + 256] - Tj[lane + 256];
            td = fmaf(df, df, td);
        }
        float dp = 0.f;
        if (lane < 20) {
            float df = xs[(size_t)i * 24 + lane] - xs[(size_t)j * 24 + lane];
            dp = df * df;
        }
#pragma unroll
        for (int off = 32; off >= 1; off >>= 1) {
            td += __shfl_xor(td, off);
            dp += __shfl_xor(dp, off);
        }
        if (lane == 0) {
            float eij = expf(-0.5f * dp);
            float sgn = (labels[j] == labels[i]) ? eij : -eij;
            acc += (double)sgn * (double)td;
        }
    }
    __shared__ double wsum[4];
    if (lane == 0) wsum[wid] = acc;
    __syncthreads();
    if (threadIdx.x == 0)
        partials[blockIdx.x] = wsum[0] + wsum[1] + wsum[2] + wsum[3];
}

// ---- Stage 5: deterministic final reduce + mean ----------------------------
__global__ __launch_bounds__(1024) void finalize_kernel(const double* __restrict__ partials,
                                                        int nparts, float* __restrict__ out) {
    __shared__ double red[1024];
    int t = threadIdx.x;
    double s = 0.0;
    for (int q = t; q < nparts; q += 1024) s += partials[q];
    red[t] = s;
    __syncthreads();
    for (int sft = 512; sft > 0; sft >>= 1) {
        if (t < sft) red[t] += red[t + sft];
        __syncthreads();
    }
    if (t == 0) out[0] = (float)(red[0] / (double)PAIRS);
}

extern "C" void kernel_launch(void* const* d_in, const int* in_sizes, int n_in,
                              void* d_out, int out_size, void* d_ws, size_t ws_size,
                              hipStream_t stream) {
    const float* logits = (const float*)d_in[0];
    const int*   labels = (const int*)d_in[1];
    const float* insT   = (const float*)d_in[2];
    float* out = (float*)d_out;

    char* ws = (char*)d_ws;
    const int NPAIRBLK = PAIRS / (8 * 4);                    // 3584
    double*         partials = (double*)ws;                  // 28672 B
    int*            nidx     = (int*)(ws + 32768);           // 458752 B
    float*          sq       = (float*)(ws + 32768 + 458752);
    unsigned short* xb       = (unsigned short*)(ws + 32768 + 458752 + 65536);
    float*          xs       = (float*)(ws + 32768 + 458752 + 65536 + 1048576);
    float*          parts_d  = (float*)(ws + 32768 + 458752 + 65536 + 1048576 + 1572864);
    int*            parts_i  = (int*)(ws + 32768 + 458752 + 65536 + 1048576 + 1572864 + 2097152);

    hipLaunchKernelGGL(prep_kernel, dim3(NPTS / 256), dim3(256), 0, stream,
                       logits, xs, xb, sq);
    hipLaunchKernelGGL(topk_mfma_kernel, dim3(256, SLC), dim3(256), 0, stream,
                       xb, sq, parts_d, parts_i);
    hipLaunchKernelGGL(merge_kernel, dim3(NPTS / 4), dim3(256), 0, stream,
                       parts_d, parts_i, nidx);
    hipLaunchKernelGGL(pair_kernel, dim3(NPAIRBLK), dim3(256), 0, stream,
                       xs, labels, insT, nidx, partials);
    hipLaunchKernelGGL(finalize_kernel, dim3(1), dim3(1024), 0, stream,
                       partials, NPAIRBLK, out);
}

// Round 4
// 122.237 us; speedup vs baseline: 2.7237x; 1.3668x over previous
//
#include <hip/hip_runtime.h>

#define BB 4
#define CC 17
#define NN 4096
#define KN 7
#define NPTS (BB*NN)             // 16384
#define PAIRS (NPTS*KN)          // 114688
#define TT (CC*CC)               // 289
#define FINF 3.4e38f

typedef float f32x4 __attribute__((ext_vector_type(4)));
typedef short short8 __attribute__((ext_vector_type(8)));

// ---- Stage 1: transpose logits -> xs fp32[16384][24], xb bf16[16384][32], sq
__global__ __launch_bounds__(256) void prep_kernel(const float* __restrict__ logits,
                                                   float* __restrict__ xs,
                                                   unsigned short* __restrict__ xb,
                                                   float* __restrict__ sq) {
    int i = blockIdx.x * blockDim.x + threadIdx.x;
    if (i >= NPTS) return;
    int b = i >> 12;
    int n = i & (NN - 1);
    const float* base = logits + (size_t)b * CC * NN + n;
    float v[24];
    float s = 0.f;
#pragma unroll
    for (int c = 0; c < CC; ++c) { v[c] = base[(size_t)c * NN]; s = fmaf(v[c], v[c], s); }
#pragma unroll
    for (int c = CC; c < 24; ++c) v[c] = 0.f;
    float4* dst = (float4*)(xs + (size_t)i * 24);
#pragma unroll
    for (int q = 0; q < 6; ++q)
        dst[q] = make_float4(v[4*q], v[4*q+1], v[4*q+2], v[4*q+3]);
    sq[i] = s;
    unsigned int w[16];
#pragma unroll
    for (int t = 0; t < 16; ++t) {
        unsigned int u0 = 0, u1 = 0;
        if (2*t < CC)     { unsigned int ub = __float_as_uint(v[2*t]);   u0 = (ub + 0x7FFFu + ((ub>>16)&1u)) >> 16; }
        if (2*t+1 < CC)   { unsigned int ub = __float_as_uint(v[2*t+1]); u1 = (ub + 0x7FFFu + ((ub>>16)&1u)) >> 16; }
        w[t] = u0 | (u1 << 16);
    }
    uint4* xd = (uint4*)(xb + (size_t)i * 32);
#pragma unroll
    for (int q = 0; q < 4; ++q)
        xd[q] = make_uint4(w[4*q], w[4*q+1], w[4*q+2], w[4*q+3]);
}

// ---- Stage 2: MFMA ranks, two passes: (1) per-row 8th-best bound, (2) filter+append
__global__ __launch_bounds__(256) void topk_filter_kernel(const unsigned short* __restrict__ xb,
                                                          const float* __restrict__ sq,
                                                          float* __restrict__ surv_d,
                                                          int* __restrict__ surv_i,
                                                          int* __restrict__ cntg,
                                                          int S, int CSL, int CAP) {
    int wid   = threadIdx.x >> 6;
    int lane  = threadIdx.x & 63;
    int strip = blockIdx.x * 4 + wid;      // 0..1023 (16 rows each)
    int s     = blockIdx.y;                // slice
    int b     = strip >> 8;
    int cb    = b * NN + s * CSL;
    int col   = lane & 15;
    int grp   = lane >> 4;
    int k0    = grp * 8;
    int ntil  = CSL >> 4;

    int arow = strip * 16 + col;
    short8 A = *reinterpret_cast<const short8*>(xb + (size_t)arow * 32 + k0);
    const unsigned short* bp = xb + (size_t)(cb + col) * 32 + k0;
    const float* sp = sq + cb + col;

    f32x4 z = {0.f, 0.f, 0.f, 0.f};

    // ---- Pass 1: per-lane stream min per row (j) ----
    float mnv[4] = {FINF, FINF, FINF, FINF};
    {
        const unsigned short* bpt = bp;
        const float* spt = sp;
#pragma unroll 4
        for (int t = 0; t < ntil; ++t) {
            short8 Bf = *reinterpret_cast<const short8*>(bpt);
            float sqv = *spt;
            f32x4 acc = __builtin_amdgcn_mfma_f32_16x16x32_bf16(A, Bf, z, 0, 0, 0);
#pragma unroll
            for (int j = 0; j < 4; ++j)
                mnv[j] = fminf(mnv[j], fmaf(-2.f, acc[j], sqv));
            bpt += 512; spt += 16;
        }
    }

    // threshold = 8th smallest of the 16 lane-mins (valid upper bound on row 8th-best)
    float thr[4];
#pragma unroll
    for (int j = 0; j < 4; ++j) {
        float v = mnv[j]; float m8 = FINF;
#pragma unroll
        for (int r = 0; r < 8; ++r) {
            float d = v;
            d = fminf(d, __shfl_xor(d, 1));
            d = fminf(d, __shfl_xor(d, 2));
            d = fminf(d, __shfl_xor(d, 4));
            d = fminf(d, __shfl_xor(d, 8));
            m8 = d;
            if (v == d) v = FINF;
        }
        thr[j] = m8 + fmaxf(fabsf(m8), 1.f) * 1e-6f;
    }

    size_t rb[4]; int cnt[4] = {0, 0, 0, 0};
#pragma unroll
    for (int j = 0; j < 4; ++j)
        rb[j] = ((size_t)(strip * 16 + grp * 4 + j) * S + s) * CAP;

    // ---- Pass 2: recompute, filter, deterministic ballot-append ----
    {
        const unsigned short* bpt = bp;
        const float* spt = sp;
#pragma unroll 2
        for (int t = 0; t < ntil; ++t) {
            short8 Bf = *reinterpret_cast<const short8*>(bpt);
            float sqv = *spt;
            f32x4 acc = __builtin_amdgcn_mfma_f32_16x16x32_bf16(A, Bf, z, 0, 0, 0);
#pragma unroll
            for (int j = 0; j < 4; ++j) {
                float r = fmaf(-2.f, acc[j], sqv);
                bool pass = r < thr[j];
                unsigned long long mb = __ballot(pass);
                unsigned gm = (unsigned)(mb >> (grp * 16)) & 0xFFFFu;
                if (pass) {
                    int off  = __popc(gm & ((1u << col) - 1u));
                    int slot = cnt[j] + off;
                    if (slot < CAP) {
                        surv_d[rb[j] + slot] = r;
                        surv_i[rb[j] + slot] = cb + (t << 4) + col;
                    }
                }
                cnt[j] += __popc(gm);
            }
            bpt += 512; spt += 16;
        }
    }

    if (col == 0) {
#pragma unroll
        for (int j = 0; j < 4; ++j)
            cntg[(strip * 16 + grp * 4 + j) * S + s] = cnt[j];
    }
}

__device__ __forceinline__ bool lexless(float ad, int ai, float bd, int bi) {
    return (ad < bd) || (ad == bd && ai < bi);
}

// ---- Stage 3: per-row top-8 of survivors, drop self (min), emit 7 idx -----
__global__ __launch_bounds__(256) void merge_kernel(const float* __restrict__ surv_d,
                                                    const int* __restrict__ surv_i,
                                                    const int* __restrict__ cntg,
                                                    int* __restrict__ nidx,
                                                    int S, int CAP, int LOGCAP) {
    int wid  = threadIdx.x >> 6;
    int lane = threadIdx.x & 63;
    int row  = blockIdx.x * 4 + wid;
    int P    = S * CAP;                    // <= 256
    const float* pd = surv_d + (size_t)row * P;
    const int*   pi = surv_i + (size_t)row * P;
    const int*   pc = cntg + row * S;

    float d[4]; int ii[4];
#pragma unroll
    for (int q = 0; q < 4; ++q) {
        int slot = lane + 64 * q;
        d[q] = FINF; ii[q] = 0x40000000 + slot;
        if (slot < P) {
            int sl = slot >> LOGCAP;
            int k  = slot & (CAP - 1);
            int c  = pc[sl]; c = (c > CAP) ? CAP : c;
            if (k < c) { d[q] = pd[slot]; ii[q] = pi[slot]; }
        }
    }
#define CE(a,b) if (lexless(d[b], ii[b], d[a], ii[a])) { float td=d[a];d[a]=d[b];d[b]=td; int ti=ii[a];ii[a]=ii[b];ii[b]=ti; }
    CE(0,1) CE(2,3) CE(0,2) CE(1,3) CE(1,2)
#undef CE

#pragma unroll
    for (int r = 0; r < 8; ++r) {
        float g = d[0]; int gi = ii[0];
#pragma unroll
        for (int off = 32; off >= 1; off >>= 1) {
            float od = __shfl_xor(g, off);
            int   oi = __shfl_xor(gi, off);
            if (lexless(od, oi, g, gi)) { g = od; gi = oi; }
        }
        if (r >= 1 && lane == 0) nidx[(size_t)row * KN + (r - 1)] = gi;
        if (ii[0] == gi) {
            d[0] = d[1]; ii[0] = ii[1];
            d[1] = d[2]; ii[1] = ii[2];
            d[2] = d[3]; ii[2] = ii[3];
            d[3] = FINF; ii[3] = 0x50000000 + lane * 8 + r;
        }
    }
}

// ---- Stage 4: wave-per-pair, coalesced T-row scan, 8 pairs per wave --------
__global__ __launch_bounds__(256) void pair_kernel(const float* __restrict__ xs,
                                                   const int* __restrict__ labels,
                                                   const float* __restrict__ insT,
                                                   const int* __restrict__ nidx,
                                                   double* __restrict__ partials) {
    int wid  = threadIdx.x >> 6;
    int lane = threadIdx.x & 63;
    int wv   = blockIdx.x * 4 + wid;
    double acc = 0.0;
#pragma unroll 1
    for (int pp = 0; pp < 8; ++pp) {
        int p = wv * 8 + pp;
        int i = p / KN;
        int j = nidx[p];
        const float* Ti = insT + (size_t)i * TT;
        const float* Tj = insT + (size_t)j * TT;
        float td = 0.f;
#pragma unroll
        for (int q = 0; q < 4; ++q) {
            int e = lane + 64 * q;
            float df = Ti[e] - Tj[e];
            td = fmaf(df, df, td);
        }
        if (lane < TT - 256) {
            float df = Ti[lane + 256] - Tj[lane + 256];
            td = fmaf(df, df, td);
        }
        float dp = 0.f;
        if (lane < 20) {
            float df = xs[(size_t)i * 24 + lane] - xs[(size_t)j * 24 + lane];
            dp = df * df;
        }
#pragma unroll
        for (int off = 32; off >= 1; off >>= 1) {
            td += __shfl_xor(td, off);
            dp += __shfl_xor(dp, off);
        }
        if (lane == 0) {
            float eij = expf(-0.5f * dp);
            float sgn = (labels[j] == labels[i]) ? eij : -eij;
            acc += (double)sgn * (double)td;
        }
    }
    __shared__ double wsum[4];
    if (lane == 0) wsum[wid] = acc;
    __syncthreads();
    if (threadIdx.x == 0)
        partials[blockIdx.x] = wsum[0] + wsum[1] + wsum[2] + wsum[3];
}

// ---- Stage 5: deterministic final reduce + mean ----------------------------
__global__ __launch_bounds__(1024) void finalize_kernel(const double* __restrict__ partials,
                                                        int nparts, float* __restrict__ out) {
    __shared__ double red[1024];
    int t = threadIdx.x;
    double s = 0.0;
    for (int q = t; q < nparts; q += 1024) s += partials[q];
    red[t] = s;
    __syncthreads();
    for (int sft = 512; sft > 0; sft >>= 1) {
        if (t < sft) red[t] += red[t + sft];
        __syncthreads();
    }
    if (t == 0) out[0] = (float)(red[0] / (double)PAIRS);
}

extern "C" void kernel_launch(void* const* d_in, const int* in_sizes, int n_in,
                              void* d_out, int out_size, void* d_ws, size_t ws_size,
                              hipStream_t stream) {
    const float* logits = (const float*)d_in[0];
    const int*   labels = (const int*)d_in[1];
    const float* insT   = (const float*)d_in[2];
    float* out = (float*)d_out;

    const size_t o_partials = 0;
    const size_t o_nidx     = 32768;
    const size_t o_sq       = o_nidx + 458752;
    const size_t o_xb       = o_sq + 65536;
    const size_t o_xs       = o_xb + 1048576;
    const size_t o_cnt      = o_xs + 1572864;       // base = 3,178,496

    // ladder on workspace: (S,CAP) = (8,32) -> (4,32) -> (4,16) -> (2,16) -> (2,8)
    int S = 8, CAP = 32;
    {
        auto need = [&](int S_, int C_) {
            return o_cnt + (size_t)NPTS * S_ * 4 + 2 * (size_t)NPTS * S_ * C_ * 4;
        };
        if (need(S, CAP) > ws_size) { S = 4; CAP = 32; }
        if (need(S, CAP) > ws_size) { S = 4; CAP = 16; }
        if (need(S, CAP) > ws_size) { S = 2; CAP = 16; }
        if (need(S, CAP) > ws_size) { S = 2; CAP = 8; }
    }
    int LOGCAP = (CAP == 32) ? 5 : ((CAP == 16) ? 4 : 3);
    int CSL = NN / S;

    char* ws = (char*)d_ws;
    const int NPAIRBLK = PAIRS / (8 * 4);            // 3584
    double* partials = (double*)(ws + o_partials);
    int*    nidx     = (int*)(ws + o_nidx);
    float*  sq       = (float*)(ws + o_sq);
    unsigned short* xb = (unsigned short*)(ws + o_xb);
    float*  xs       = (float*)(ws + o_xs);
    int*    cntg     = (int*)(ws + o_cnt);
    float*  surv_d   = (float*)(ws + o_cnt + (size_t)NPTS * S * 4);
    int*    surv_i   = (int*)(ws + o_cnt + (size_t)NPTS * S * 4 + (size_t)NPTS * S * CAP * 4);

    hipLaunchKernelGGL(prep_kernel, dim3(NPTS / 256), dim3(256), 0, stream,
                       logits, xs, xb, sq);
    hipLaunchKernelGGL(topk_filter_kernel, dim3(256, S), dim3(256), 0, stream,
                       xb, sq, surv_d, surv_i, cntg, S, CSL, CAP);
    hipLaunchKernelGGL(merge_kernel, dim3(NPTS / 4), dim3(256), 0, stream,
                       surv_d, surv_i, cntg, nidx, S, CAP, LOGCAP);
    hipLaunchKernelGGL(pair_kernel, dim3(NPAIRBLK), dim3(256), 0, stream,
                       xs, labels, insT, nidx, partials);
    hipLaunchKernelGGL(finalize_kernel, dim3(1), dim3(1024), 0, stream,
                       partials, NPAIRBLK, out);
}